// Round 1
// baseline (312.362 us; speedup 1.0000x reference)
//
#include <hip/hip_runtime.h>
#include <hip/hip_bf16.h>

typedef __bf16 bf16x8 __attribute__((ext_vector_type(8)));
typedef float  f32x4  __attribute__((ext_vector_type(4)));

#define B_SZ    1024
#define COUT_SZ 512
#define K_SZ    32768   // G * CIN = 64 * 512
#define TM 128
#define TN 128
#define BK 32

// async 16B global -> LDS (DMA, no VGPR round trip). LDS dest must be
// wave-uniform base; HW writes lane l at base + l*16.
__device__ __forceinline__ void async_copy16(const void* g, void* l) {
  __builtin_amdgcn_global_load_lds(
      (const __attribute__((address_space(1))) unsigned int*)g,
      (__attribute__((address_space(3))) unsigned int*)l, 16, 0, 0);
}

// ---------------------------------------------------------------------------
// Prepass: W fp32 [k=g*512+c][o=512] -> Wt bf16 [o=512][k=32768]
// 64x64 tiles through LDS; coalesced fp32 reads, coalesced 16B bf16 writes.
// ---------------------------------------------------------------------------
__global__ __launch_bounds__(256) void wtrans_kernel(
    const float* __restrict__ w, __bf16* __restrict__ wt) {
  __shared__ __bf16 t[64 * 72];  // [o_local][k_local], pitch 72 (16B-aligned rows, conflict-spread)
  const int kb = blockIdx.x * 64;
  const int ob = blockIdx.y * 64;
  const int tid = threadIdx.x;

  // load 4 k-rows x 4 o-cols per thread (coalesced: 16 lanes cover a 64-float row)
  const int o4 = (tid & 15) * 4;
  const int k0 = (tid >> 4) * 4;
  const float* src = w + (size_t)(kb + k0) * COUT_SZ + ob + o4;
  f32x4 v0 = *(const f32x4*)(src);
  f32x4 v1 = *(const f32x4*)(src + COUT_SZ);
  f32x4 v2 = *(const f32x4*)(src + 2 * COUT_SZ);
  f32x4 v3 = *(const f32x4*)(src + 3 * COUT_SZ);
#pragma unroll
  for (int c = 0; c < 4; ++c) {
    union { __bf16 h[4]; unsigned long long u; } p;
    p.h[0] = (__bf16)v0[c]; p.h[1] = (__bf16)v1[c];
    p.h[2] = (__bf16)v2[c]; p.h[3] = (__bf16)v3[c];
    *(unsigned long long*)&t[(o4 + c) * 72 + k0] = p.u;  // transposed store, b64
  }
  __syncthreads();

  // write out: thread -> (o_row, 32B k-chunk); 4 lanes cover one 128B row
  const int o  = tid >> 2;
  const int kc = (tid & 3) * 16;
  const uint4* s0 = (const uint4*)&t[o * 72 + kc];
  uint4 a = s0[0];
  uint4 b = s0[1];
  uint4* dst = (uint4*)(wt + (size_t)(ob + o) * K_SZ + kb + kc);
  dst[0] = a;
  dst[1] = b;
}

// ---------------------------------------------------------------------------
// Split-K GEMM: 128x128 tile, BK=32, 256 threads (4 waves, each 64x64 = 4x4
// subtiles of 16x16x32 bf16 MFMA). A (x) staged as fp32 via global_load_lds,
// converted to bf16 at fragment load; B (Wt) staged as bf16 via
// global_load_lds. Partials (one 1024x512 fp32 slice per z) to ws.
// Block swizzle: m-tile == blockIdx&7 -> one x-strip per XCD (L2 locality);
// the 4 n-siblings of an A-chunk are launch-adjacent on the same XCD.
// ---------------------------------------------------------------------------
__global__ __launch_bounds__(256, 2)
void gemm_kernel(const float* __restrict__ x, const __bf16* __restrict__ wt,
                 float* __restrict__ dst, int kchunk) {
  __shared__ float  As[TM * BK];   // fp32 A tile, rows of 32 floats (128B), 16 KB
  __shared__ __bf16 Bs[TN * BK];   // bf16 B tile (k-contiguous rows of 64B), 8 KB

  const int lin = blockIdx.x;
  const int m0 = (lin & 7) * TM;          // 8 m-tiles <-> 8 XCDs
  const int n0 = ((lin >> 3) & 3) * TN;   // 4 n-tiles
  const int z  = lin >> 5;                // split index
  const int tid  = threadIdx.x;
  const int wave = tid >> 6;
  const int lane = tid & 63;

  const int kbase = z * kchunk;

  // --- staging source pointers (advance by BK per iter) ---
  // A: issue i covers fp32 chunk block (wave*4+i)*1024B; lane l -> row
  //    m=(wave*4+i)*8 + (l>>3), k-offset (l&7)*4.
  const float* ag0 = x + (size_t)(m0 + (wave * 4 + 0) * 8 + (lane >> 3)) * K_SZ + kbase + (lane & 7) * 4;
  const float* ag1 = x + (size_t)(m0 + (wave * 4 + 1) * 8 + (lane >> 3)) * K_SZ + kbase + (lane & 7) * 4;
  const float* ag2 = x + (size_t)(m0 + (wave * 4 + 2) * 8 + (lane >> 3)) * K_SZ + kbase + (lane & 7) * 4;
  const float* ag3 = x + (size_t)(m0 + (wave * 4 + 3) * 8 + (lane >> 3)) * K_SZ + kbase + (lane & 7) * 4;
  // B: issue i covers bf16 chunk block (wave*2+i)*1024B; lane l -> row
  //    n=(wave*2+i)*16 + (l>>2), k-offset (l&3)*8.
  const __bf16* bg0 = wt + (size_t)(n0 + (wave * 2 + 0) * 16 + (lane >> 2)) * K_SZ + kbase + (lane & 3) * 8;
  const __bf16* bg1 = wt + (size_t)(n0 + (wave * 2 + 1) * 16 + (lane >> 2)) * K_SZ + kbase + (lane & 3) * 8;

  float* aL0 = &As[(wave * 4 + 0) * 256];
  float* aL1 = &As[(wave * 4 + 1) * 256];
  float* aL2 = &As[(wave * 4 + 2) * 256];
  float* aL3 = &As[(wave * 4 + 3) * 256];
  __bf16* bL0 = &Bs[(wave * 2 + 0) * 512];
  __bf16* bL1 = &Bs[(wave * 2 + 1) * 512];

  // --- fragment geometry ---
  const int lm = lane & 15;      // C/D col, A/B row index within 16
  const int q  = lane >> 4;      // quad: k0 = q*8, C/D row base q*4
  const int wm = (wave & 1) * 64;
  const int wn = (wave >> 1) * 64;

  f32x4 acc[4][4];
#pragma unroll
  for (int i = 0; i < 4; ++i)
#pragma unroll
    for (int j = 0; j < 4; ++j)
      acc[i][j] = (f32x4){0.f, 0.f, 0.f, 0.f};

  const int niter = kchunk / BK;
  for (int it = 0; it < niter; ++it) {
    async_copy16(ag0, aL0);
    async_copy16(ag1, aL1);
    async_copy16(ag2, aL2);
    async_copy16(ag3, aL3);
    async_copy16(bg0, bL0);
    async_copy16(bg1, bL1);
    ag0 += BK; ag1 += BK; ag2 += BK; ag3 += BK;
    bg0 += BK; bg1 += BK;
    __syncthreads();  // drains vmcnt -> LDS tiles complete

    bf16x8 af[4], bfr[4];
#pragma unroll
    for (int i = 0; i < 4; ++i) {
      const float* ap = &As[(wm + i * 16 + lm) * BK + q * 8];
      f32x4 lo = *(const f32x4*)ap;
      f32x4 hi = *(const f32x4*)(ap + 4);
      bf16x8 a;
#pragma unroll
      for (int e = 0; e < 4; ++e) {
        a[e]     = (__bf16)lo[e];
        a[e + 4] = (__bf16)hi[e];
      }
      af[i] = a;
    }
#pragma unroll
    for (int j = 0; j < 4; ++j)
      bfr[j] = *(const bf16x8*)&Bs[(wn + j * 16 + lm) * BK + q * 8];

#pragma unroll
    for (int i = 0; i < 4; ++i)
#pragma unroll
      for (int j = 0; j < 4; ++j)
        acc[i][j] = __builtin_amdgcn_mfma_f32_16x16x32_bf16(af[i], bfr[j], acc[i][j], 0, 0, 0);

    __syncthreads();  // protect LDS from next iter's staging
  }

  // epilogue: C/D layout col=lane&15, row=(lane>>4)*4+reg  [m89-verified]
  float* outp = dst + (size_t)z * (B_SZ * COUT_SZ)
              + (size_t)(m0 + wm + q * 4) * COUT_SZ + (n0 + wn + lm);
#pragma unroll
  for (int i = 0; i < 4; ++i) {
#pragma unroll
    for (int r = 0; r < 4; ++r) {
      float* o2 = outp + (size_t)(i * 16 + r) * COUT_SZ;
#pragma unroll
      for (int j = 0; j < 4; ++j)
        o2[j * 16] = acc[i][j][r];
    }
  }
}

// ---------------------------------------------------------------------------
// Reduce S partial slices + apply 1/sqrt(512) scale.
// ---------------------------------------------------------------------------
__global__ __launch_bounds__(256) void reduce_kernel(
    const float* __restrict__ p, float* __restrict__ out, int S, float scale) {
  const int i = (blockIdx.x * 256 + threadIdx.x) * 4;
  f32x4 s = (f32x4){0.f, 0.f, 0.f, 0.f};
  for (int zz = 0; zz < S; ++zz) {
    f32x4 v = *(const f32x4*)(p + (size_t)zz * (B_SZ * COUT_SZ) + i);
    s = s + v;
  }
  s = s * scale;
  *(f32x4*)(out + i) = s;
}

extern "C" void kernel_launch(void* const* d_in, const int* in_sizes, int n_in,
                              void* d_out, int out_size, void* d_ws, size_t ws_size,
                              hipStream_t stream) {
  const float* x = (const float*)d_in[0];
  const float* w = (const float*)d_in[1];
  float* out = (float*)d_out;

  const size_t wtB    = (size_t)COUT_SZ * K_SZ * sizeof(__bf16);   // 33.5 MB
  const size_t sliceB = (size_t)B_SZ * COUT_SZ * sizeof(float);    // 2 MB

  __bf16* wt = (__bf16*)d_ws;
  int S = 16;  // 512 blocks = 2/CU; kchunk = 2048 (4 groups)
  while (S > 1 && wtB + (size_t)S * sliceB > ws_size) S >>= 1;
  float* partials = (float*)((char*)d_ws + wtB);
  if (wtB + sliceB > ws_size) { partials = out; S = 1; }  // last-resort: out as the single slice

  const float scale = 0.04419417382415922f;  // 1/sqrt(512)

  hipLaunchKernelGGL(wtrans_kernel, dim3(K_SZ / 64, COUT_SZ / 64), dim3(256), 0,
                     stream, w, wt);
  hipLaunchKernelGGL(gemm_kernel, dim3(32 * S), dim3(256), 0, stream,
                     x, wt, partials, K_SZ / S);
  hipLaunchKernelGGL(reduce_kernel, dim3(B_SZ * COUT_SZ / 1024), dim3(256), 0,
                     stream, partials, out, S, scale);
}